// Round 4
// baseline (70.342 us; speedup 1.0000x reference)
//
#include <hip/hip_runtime.h>

typedef __bf16 bf16x8 __attribute__((ext_vector_type(8)));
typedef float  f32x16 __attribute__((ext_vector_type(16)));
typedef unsigned int uint4v __attribute__((ext_vector_type(4)));

#define MFMA32(A, B, C) __builtin_amdgcn_mfma_f32_32x32x16_bf16((A), (B), (C), 0, 0, 0)

__device__ __forceinline__ bf16x8 load8_bf(const float* __restrict__ p, float scale) {
    const float4 a = *reinterpret_cast<const float4*>(p);
    const float4 b = *reinterpret_cast<const float4*>(p + 4);
    bf16x8 r;
    r[0] = (__bf16)(a.x * scale); r[1] = (__bf16)(a.y * scale);
    r[2] = (__bf16)(a.z * scale); r[3] = (__bf16)(a.w * scale);
    r[4] = (__bf16)(b.x * scale); r[5] = (__bf16)(b.y * scale);
    r[6] = (__bf16)(b.z * scale); r[7] = (__bf16)(b.w * scale);
    return r;
}

__device__ __forceinline__ unsigned pack2(float a, float b) {
    unsigned la = (unsigned)__builtin_bit_cast(unsigned short, (__bf16)a);
    unsigned lb = (unsigned)__builtin_bit_cast(unsigned short, (__bf16)b);
    return la | (lb << 16);
}

__device__ __forceinline__ void swap32(unsigned& a, unsigned& b) {
#if __has_builtin(__builtin_amdgcn_permlane32_swap)
    auto r = __builtin_amdgcn_permlane32_swap(a, b, false, false);
    a = r[0]; b = r[1];
#else
    asm("v_permlane32_swap_b32 %0, %1" : "+v"(a), "+v"(b));
#endif
}

// C-layout acc (lane holds M[col][r(e,hi)], r(e,hi)=(e&3)+8*(e>>2)+4*hi)
// -> MFMA A/B fragments (lane holds M[col][k], f0: k=hi*8+q, f1: k=16+hi*8+q).
// PROVEN in Round 2 (passed, absmax 0.047).
__device__ __forceinline__ void rearrange(const f32x16& a, bf16x8& f0, bf16x8& f1) {
    unsigned D0 = pack2(a[0], a[1]),   D1 = pack2(a[2], a[3]);
    unsigned D2 = pack2(a[4], a[5]),   D3 = pack2(a[6], a[7]);
    unsigned D4 = pack2(a[8], a[9]),   D5 = pack2(a[10], a[11]);
    unsigned D6 = pack2(a[12], a[13]), D7 = pack2(a[14], a[15]);
    swap32(D0, D2); swap32(D1, D3); swap32(D4, D6); swap32(D5, D7);
    f0 = __builtin_bit_cast(bf16x8, uint4v{D0, D1, D2, D3});
    f1 = __builtin_bit_cast(bf16x8, uint4v{D4, D5, D6, D7});
}

__device__ __forceinline__ void ld4(const float* __restrict__ p,
                                    float4& r0, float4& r1, float4& r2, float4& r3) {
    r0 = *reinterpret_cast<const float4*>(p);
    r1 = *reinterpret_cast<const float4*>(p + 4);
    r2 = *reinterpret_cast<const float4*>(p + 16);
    r3 = *reinterpret_cast<const float4*>(p + 20);
}

__device__ __forceinline__ void cvt8(const float4& a, const float4& b, bf16x8& f) {
    f[0] = (__bf16)a.x; f[1] = (__bf16)a.y; f[2] = (__bf16)a.z; f[3] = (__bf16)a.w;
    f[4] = (__bf16)b.x; f[5] = (__bf16)b.y; f[6] = (__bf16)b.z; f[7] = (__bf16)b.w;
}

// Round-2-proven math, run for two batches per wave (ILP), one-shot waves.
// Bisect round: NO rearrange_bias, NO deferred-norm softmax, NO paired stores.
__global__ __launch_bounds__(256) void attn32(
    const float* __restrict__ x,
    const float* __restrict__ Wk, const float* __restrict__ bk,
    const float* __restrict__ Wq, const float* __restrict__ bq,
    const float* __restrict__ Wv, const float* __restrict__ bv,
    const float* __restrict__ Wp, const float* __restrict__ bp,
    float* __restrict__ out, int Btot)
{
    const int lane = threadIdx.x & 63;
    const int col  = lane & 31;
    const int hi   = lane >> 5;

    // XCD-chunked block swizzle (gridDim.x % 8 == 0 guaranteed by launcher)
    const unsigned g = blockIdx.x;
    const unsigned swz = (g & 7) * (gridDim.x >> 3) + (g >> 3);
    const int pairIdx = (int)swz * 4 + (threadIdx.x >> 6);
    const int bA = pairIdx * 2;
    if (bA >= Btot) return;
    const int bB = bA + 1;
    const bool hasB = bB < Btot;

    const int wrow = col * 32 + hi * 8;

    // x loads first (HBM); weights/biases are L2/L3-resident
    float4 A0, A1, A2, A3, B0, B1, B2, B3;
    ld4(x + (size_t)bA * 1024 + wrow, A0, A1, A2, A3);
    ld4(x + (size_t)(hasB ? bB : bA) * 1024 + wrow, B0, B1, B2, B3);

    // fold 1/sqrt(32)*log2(e) into Q so softmax uses exp2 directly
    const float SC = 0.17677669529663687f * 1.4426950408889634f;

    const bf16x8 wk0 = load8_bf(Wk + wrow, 1.f), wk1 = load8_bf(Wk + wrow + 16, 1.f);
    const bf16x8 wq0 = load8_bf(Wq + wrow, SC),  wq1 = load8_bf(Wq + wrow + 16, SC);
    const bf16x8 wv0 = load8_bf(Wv + wrow, 1.f), wv1 = load8_bf(Wv + wrow + 16, 1.f);
    const bf16x8 wp0 = load8_bf(Wp + wrow, 1.f), wp1 = load8_bf(Wp + wrow + 16, 1.f);

    // per-ELEMENT bias vectors for transposed-compute accumulators (Round-2 form)
    f32x16 bk16, bq16, bv16;
#pragma unroll
    for (int e = 0; e < 16; ++e) {
        const int r = (e & 3) + 8 * (e >> 2) + 4 * hi;
        bk16[e] = bk[r];
        bq16[e] = bq[r] * SC;
        bv16[e] = bv[r];
    }
    const float bpv = bp[col];

    bf16x8 xaA0, xaA1, xaB0, xaB1;
    cvt8(A0, A1, xaA0); cvt8(A2, A3, xaA1);
    cvt8(B0, B1, xaB0); cvt8(B2, B3, xaB1);

    f32x16 acc;

    // K^T = Wk * X^T + bk
    acc = bk16; acc = MFMA32(wk0, xaA0, acc); acc = MFMA32(wk1, xaA1, acc);
    bf16x8 kaA0, kaA1; rearrange(acc, kaA0, kaA1);
    acc = bk16; acc = MFMA32(wk0, xaB0, acc); acc = MFMA32(wk1, xaB1, acc);
    bf16x8 kaB0, kaB1; rearrange(acc, kaB0, kaB1);

    // Q^T (scale+log2e folded)
    acc = bq16; acc = MFMA32(wq0, xaA0, acc); acc = MFMA32(wq1, xaA1, acc);
    bf16x8 qbA0, qbA1; rearrange(acc, qbA0, qbA1);
    acc = bq16; acc = MFMA32(wq0, xaB0, acc); acc = MFMA32(wq1, xaB1, acc);
    bf16x8 qbB0, qbB1; rearrange(acc, qbB0, qbB1);

    // S^T = K * Q^T : lane (query=col) holds S'[query][key=r(e,hi)]
    f32x16 sA, sB;
#pragma unroll
    for (int e = 0; e < 16; ++e) { sA[e] = 0.f; sB[e] = 0.f; }
    sA = MFMA32(kaA0, qbA0, sA); sA = MFMA32(kaA1, qbA1, sA);
    sB = MFMA32(kaB0, qbB0, sB); sB = MFMA32(kaB1, qbB1, sB);

    // V^T
    acc = bv16; acc = MFMA32(wv0, xaA0, acc); acc = MFMA32(wv1, xaA1, acc);
    bf16x8 vbA0, vbA1; rearrange(acc, vbA0, vbA1);
    acc = bv16; acc = MFMA32(wv0, xaB0, acc); acc = MFMA32(wv1, xaB1, acc);
    bf16x8 vbB0, vbB1; rearrange(acc, vbB0, vbB1);

    // causal mask + max-subtracted softmax (Round-2 form), both batches
    f32x16 pvA, pvB;
    {
        float svA[16], svB[16];
        float mA = -3.0e38f, mB = -3.0e38f;
#pragma unroll
        for (int e = 0; e < 16; ++e) {
            const int j = (e & 3) + 8 * (e >> 2) + 4 * hi;
            svA[e] = (j <= col) ? sA[e] : -__builtin_inff();
            svB[e] = (j <= col) ? sB[e] : -__builtin_inff();
            mA = fmaxf(mA, svA[e]);
            mB = fmaxf(mB, svB[e]);
        }
        mA = fmaxf(mA, __shfl_xor(mA, 32));
        mB = fmaxf(mB, __shfl_xor(mB, 32));
        float peA[16], peB[16];
        float sumA = 0.f, sumB = 0.f;
#pragma unroll
        for (int e = 0; e < 16; ++e) {
            peA[e] = __builtin_amdgcn_exp2f(svA[e] - mA); sumA += peA[e];
            peB[e] = __builtin_amdgcn_exp2f(svB[e] - mB); sumB += peB[e];
        }
        sumA += __shfl_xor(sumA, 32);
        sumB += __shfl_xor(sumB, 32);
        const float invA = __builtin_amdgcn_rcpf(sumA);
        const float invB = __builtin_amdgcn_rcpf(sumB);
#pragma unroll
        for (int e = 0; e < 16; ++e) { pvA[e] = peA[e] * invA; pvB[e] = peB[e] * invB; }
    }
    bf16x8 paA0, paA1, paB0, paB1;
    rearrange(pvA, paA0, paA1);
    rearrange(pvB, paB0, paB1);

    // Y^T = V * P^T
    f32x16 ytA, ytB;
#pragma unroll
    for (int e = 0; e < 16; ++e) { ytA[e] = 0.f; ytB[e] = 0.f; }
    ytA = MFMA32(vbA0, paA0, ytA); ytA = MFMA32(vbA1, paA1, ytA);
    ytB = MFMA32(vbB0, paB0, ytB); ytB = MFMA32(vbB1, paB1, ytB);
    bf16x8 yaA0, yaA1, yaB0, yaB1;
    rearrange(ytA, yaA0, yaA1);
    rearrange(ytB, yaB0, yaB1);

    // out = Y * Wp^T + bp
    f32x16 oA, oB;
#pragma unroll
    for (int e = 0; e < 16; ++e) { oA[e] = bpv; oB[e] = bpv; }
    oA = MFMA32(yaA0, wp0, oA); oA = MFMA32(yaA1, wp1, oA);
    oB = MFMA32(yaB0, wp0, oB); oB = MFMA32(yaB1, wp1, oB);

    // stores: Round-2-proven per-batch form. out flat [T, B, C].
    {
        float* const ob = out + (size_t)bA * 32 + col;
#pragma unroll
        for (int e = 0; e < 16; ++e) {
            const int r = (e & 3) + 8 * (e >> 2) + 4 * hi;
            __builtin_nontemporal_store(oA[e], ob + ((size_t)r << 20));
        }
    }
    if (hasB) {
        float* const ob = out + (size_t)bB * 32 + col;
#pragma unroll
        for (int e = 0; e < 16; ++e) {
            const int r = (e & 3) + 8 * (e >> 2) + 4 * hi;
            __builtin_nontemporal_store(oB[e], ob + ((size_t)r << 20));
        }
    }
}

extern "C" void kernel_launch(void* const* d_in, const int* in_sizes, int n_in,
                              void* d_out, int out_size, void* d_ws, size_t ws_size,
                              hipStream_t stream) {
    const float* x  = (const float*)d_in[0];
    const float* Wk = (const float*)d_in[1];
    const float* bk = (const float*)d_in[2];
    const float* Wq = (const float*)d_in[3];
    const float* bq = (const float*)d_in[4];
    const float* Wv = (const float*)d_in[5];
    const float* bv = (const float*)d_in[6];
    const float* Wp = (const float*)d_in[7];
    const float* bp = (const float*)d_in[8];
    float* out = (float*)d_out;

    const int Btot = in_sizes[0] / 1024;            // [B,32,32] fp32
    const int pairs = (Btot + 1) / 2;               // one wave per pair
    int blocks = (pairs + 3) / 4;                   // 4 waves per block
    blocks = (blocks + 7) & ~7;                     // keep %8==0 for swizzle
    dim3 grid(blocks), block(256);
    hipLaunchKernelGGL(attn32, grid, block, 0, stream,
                       x, Wk, bk, Wq, bq, Wv, bv, Wp, bp, out, Btot);
}

// Round 5
// 58.426 us; speedup vs baseline: 1.2040x; 1.2040x over previous
//
#include <hip/hip_runtime.h>

typedef __bf16 bf16x8 __attribute__((ext_vector_type(8)));
typedef float  f32x16 __attribute__((ext_vector_type(16)));
typedef unsigned int uint4v __attribute__((ext_vector_type(4)));

#define MFMA32(A, B, C) __builtin_amdgcn_mfma_f32_32x32x16_bf16((A), (B), (C), 0, 0, 0)

__device__ __forceinline__ bf16x8 load8_bf(const float* __restrict__ p, float scale) {
    const float4 a = *reinterpret_cast<const float4*>(p);
    const float4 b = *reinterpret_cast<const float4*>(p + 4);
    bf16x8 r;
    r[0] = (__bf16)(a.x * scale); r[1] = (__bf16)(a.y * scale);
    r[2] = (__bf16)(a.z * scale); r[3] = (__bf16)(a.w * scale);
    r[4] = (__bf16)(b.x * scale); r[5] = (__bf16)(b.y * scale);
    r[6] = (__bf16)(b.z * scale); r[7] = (__bf16)(b.w * scale);
    return r;
}

__device__ __forceinline__ unsigned pack2(float a, float b) {
    unsigned la = (unsigned)__builtin_bit_cast(unsigned short, (__bf16)a);
    unsigned lb = (unsigned)__builtin_bit_cast(unsigned short, (__bf16)b);
    return la | (lb << 16);
}

__device__ __forceinline__ void swap32(unsigned& a, unsigned& b) {
#if __has_builtin(__builtin_amdgcn_permlane32_swap)
    auto r = __builtin_amdgcn_permlane32_swap(a, b, false, false);
    a = r[0]; b = r[1];
#else
    asm("v_permlane32_swap_b32 %0, %1" : "+v"(a), "+v"(b));
#endif
}

// C-layout acc (lane holds M[col][r(e,hi)], r(e,hi)=(e&3)+8*(e>>2)+4*hi)
// -> MFMA A/B fragments (lane holds M[col][k], f0: k=hi*8+q, f1: k=16+hi*8+q).
// PROVEN (R2/R4 passed, absmax 0.047).
__device__ __forceinline__ void rearrange(const f32x16& a, bf16x8& f0, bf16x8& f1) {
    unsigned D0 = pack2(a[0], a[1]),   D1 = pack2(a[2], a[3]);
    unsigned D2 = pack2(a[4], a[5]),   D3 = pack2(a[6], a[7]);
    unsigned D4 = pack2(a[8], a[9]),   D5 = pack2(a[10], a[11]);
    unsigned D6 = pack2(a[12], a[13]), D7 = pack2(a[14], a[15]);
    swap32(D0, D2); swap32(D1, D3); swap32(D4, D6); swap32(D5, D7);
    f0 = __builtin_bit_cast(bf16x8, uint4v{D0, D1, D2, D3});
    f1 = __builtin_bit_cast(bf16x8, uint4v{D4, D5, D6, D7});
}

__device__ __forceinline__ void cvt8(const float4& a, const float4& b, bf16x8& f) {
    f[0] = (__bf16)a.x; f[1] = (__bf16)a.y; f[2] = (__bf16)a.z; f[3] = (__bf16)a.w;
    f[4] = (__bf16)b.x; f[5] = (__bf16)b.y; f[6] = (__bf16)b.z; f[7] = (__bf16)b.w;
}

// Stage one batch's 4 KB x-image into a per-wave LDS slice.
// LDS dest is linear (base + lane*16 per instr, rule m104); the XOR swizzle
// (involution A ^= ((A>>9)&7)<<4, 16B-chunk-preserving) is applied to the
// GLOBAL source so swizzled ds_read_b128 fragment reads are <=2-way conflict.
// Per instruction each 32-lane half reads one contiguous 512 B block -> fully
// coalesced (8 line-requests/instr vs 32 for the old per-row gather).
__device__ __forceinline__ void stage_x(const char* __restrict__ xb, char* lslice,
                                        const int* src_off) {
#pragma unroll
    for (int t = 0; t < 4; ++t) {
        __builtin_amdgcn_global_load_lds(
            (const __attribute__((address_space(1))) unsigned*)(xb + src_off[t]),
            (__attribute__((address_space(3))) unsigned*)(lslice + t * 1024),
            16, 0, 0);
    }
}

// R2-proven math + loop/prefetch structure; only the x path changed:
// global gather -> global_load_lds staging (coalesced) + swizzled LDS reads.
__global__ __launch_bounds__(256) void attn32(
    const float* __restrict__ x,
    const float* __restrict__ Wk, const float* __restrict__ bk,
    const float* __restrict__ Wq, const float* __restrict__ bq,
    const float* __restrict__ Wv, const float* __restrict__ bv,
    const float* __restrict__ Wp, const float* __restrict__ bp,
    float* __restrict__ out, int Btot)
{
    __shared__ char ldsx[4][2][4096];  // [wave][buf] double-buffered x image

    const int lane = threadIdx.x & 63;
    const int col  = lane & 31;
    const int hi   = lane >> 5;
    const int wave = threadIdx.x >> 6;

    const int gw = blockIdx.x * 4 + wave;
    const int nw = gridDim.x * 4;
    if (gw >= Btot) return;

    char* const buf0 = &ldsx[wave][0][0];
    char* const buf1 = &ldsx[wave][1][0];

    // staging source offsets (loop-invariant): A = t*1024 + lane*16, XOR-swizzled
    int src_off[4];
#pragma unroll
    for (int t = 0; t < 4; ++t) {
        const int A = t * 1024 + lane * 16;
        src_off[t] = A ^ (((A >> 9) & 7) << 4);
    }
    // reader offsets (loop-invariant): fragment chunks of row=col, swizzled
    const int W0 = col * 128 + hi * 32;
    const int sw = ((W0 >> 9) & 7) << 4;
    const int s0 = W0 ^ sw, s1 = (W0 + 16) ^ sw, s2 = (W0 + 64) ^ sw, s3 = (W0 + 80) ^ sw;

    // fold 1/sqrt(32)*log2(e) into Q so softmax uses exp2 directly
    const float SC = 0.17677669529663687f * 1.4426950408889634f;

    const int wrow = col * 32 + hi * 8;
    const bf16x8 wk0 = load8_bf(Wk + wrow, 1.f), wk1 = load8_bf(Wk + wrow + 16, 1.f);
    const bf16x8 wq0 = load8_bf(Wq + wrow, SC),  wq1 = load8_bf(Wq + wrow + 16, SC);
    const bf16x8 wv0 = load8_bf(Wv + wrow, 1.f), wv1 = load8_bf(Wv + wrow + 16, 1.f);
    const bf16x8 wp0 = load8_bf(Wp + wrow, 1.f), wp1 = load8_bf(Wp + wrow + 16, 1.f);

    f32x16 bk16, bq16, bv16;
#pragma unroll
    for (int e = 0; e < 16; ++e) {
        const int r = (e & 3) + 8 * (e >> 2) + 4 * hi;
        bk16[e] = bk[r];
        bq16[e] = bq[r] * SC;
        bv16[e] = bv[r];
    }
    const float bpv = bp[col];

    // prologue: stage first batch, drain once
    stage_x((const char*)(x + (size_t)gw * 1024), buf0, src_off);
    asm volatile("s_waitcnt vmcnt(0)" ::: "memory");

    bool parity = false;
    for (int b = gw; b < Btot; b += nw, parity = !parity) {
        const char* cur = parity ? buf1 : buf0;
        char* nxt       = parity ? buf0 : buf1;

        // issue next-batch staging FIRST (oldest in vmcnt FIFO before stores)
        const int nb = b + nw;
        if (nb < Btot)
            stage_x((const char*)(x + (size_t)nb * 1024), nxt, src_off);
        asm volatile("" ::: "memory");

        // fragment reads from staged image (swizzled, <=2-way banks)
        const float4 A0 = *reinterpret_cast<const float4*>(cur + s0);
        const float4 A1 = *reinterpret_cast<const float4*>(cur + s1);
        const float4 A2 = *reinterpret_cast<const float4*>(cur + s2);
        const float4 A3 = *reinterpret_cast<const float4*>(cur + s3);
        bf16x8 xa0, xa1;
        cvt8(A0, A1, xa0);
        cvt8(A2, A3, xa1);

        f32x16 acc;

        // K^T = Wk * X^T + bk
        acc = bk16; acc = MFMA32(wk0, xa0, acc); acc = MFMA32(wk1, xa1, acc);
        bf16x8 ka0, ka1; rearrange(acc, ka0, ka1);

        // Q^T (scale+log2e folded)
        acc = bq16; acc = MFMA32(wq0, xa0, acc); acc = MFMA32(wq1, xa1, acc);
        bf16x8 qb0, qb1; rearrange(acc, qb0, qb1);

        // S^T = K * Q^T : lane (query=col) holds S'[query][key=r(e,hi)]
        f32x16 s;
#pragma unroll
        for (int e = 0; e < 16; ++e) s[e] = 0.f;
        s = MFMA32(ka0, qb0, s);
        s = MFMA32(ka1, qb1, s);

        // V^T
        acc = bv16; acc = MFMA32(wv0, xa0, acc); acc = MFMA32(wv1, xa1, acc);
        bf16x8 vb0, vb1; rearrange(acc, vb0, vb1);

        // causal mask + max-subtracted softmax (R2-proven)
        f32x16 pv;
        {
            float sv[16];
            float m = -3.0e38f;
#pragma unroll
            for (int e = 0; e < 16; ++e) {
                const int j = (e & 3) + 8 * (e >> 2) + 4 * hi;
                sv[e] = (j <= col) ? s[e] : -__builtin_inff();
                m = fmaxf(m, sv[e]);
            }
            m = fmaxf(m, __shfl_xor(m, 32));
            float pe[16];
            float sum = 0.f;
#pragma unroll
            for (int e = 0; e < 16; ++e) { pe[e] = __builtin_amdgcn_exp2f(sv[e] - m); sum += pe[e]; }
            sum += __shfl_xor(sum, 32);
            const float inv = __builtin_amdgcn_rcpf(sum);
#pragma unroll
            for (int e = 0; e < 16; ++e) pv[e] = pe[e] * inv;
        }
        bf16x8 pa0, pa1; rearrange(pv, pa0, pa1);

        // Y^T = V * P^T
        f32x16 yt;
#pragma unroll
        for (int e = 0; e < 16; ++e) yt[e] = 0.f;
        yt = MFMA32(vb0, pa0, yt);
        yt = MFMA32(vb1, pa1, yt);
        bf16x8 ya0, ya1; rearrange(yt, ya0, ya1);

        // out = Y * Wp^T + bp
        f32x16 o;
#pragma unroll
        for (int e = 0; e < 16; ++e) o[e] = bpv;
        o = MFMA32(ya0, wp0, o);
        o = MFMA32(ya1, wp1, o);

        asm volatile("" ::: "memory");  // keep stores AFTER staging in FIFO

        // out flat [T, B, C]: element r*2^20 + b*32 + col (R2-proven)
        float* const ob = out + (size_t)b * 32 + col;
#pragma unroll
        for (int e = 0; e < 16; ++e) {
            const int r = (e & 3) + 8 * (e >> 2) + 4 * hi;
            __builtin_nontemporal_store(o[e], ob + ((size_t)r << 20));
        }

        // confirm staging of nxt (oldest 4 + any prior stores complete; this
        // iter's 16 stores may stay in flight — never drain to 0 in-loop)
        asm volatile("s_waitcnt vmcnt(16)" ::: "memory");
        __builtin_amdgcn_sched_barrier(0);
    }
}

extern "C" void kernel_launch(void* const* d_in, const int* in_sizes, int n_in,
                              void* d_out, int out_size, void* d_ws, size_t ws_size,
                              hipStream_t stream) {
    const float* x  = (const float*)d_in[0];
    const float* Wk = (const float*)d_in[1];
    const float* bk = (const float*)d_in[2];
    const float* Wq = (const float*)d_in[3];
    const float* bq = (const float*)d_in[4];
    const float* Wv = (const float*)d_in[5];
    const float* bv = (const float*)d_in[6];
    const float* Wp = (const float*)d_in[7];
    const float* bp = (const float*)d_in[8];
    float* out = (float*)d_out;

    const int Btot = in_sizes[0] / 1024;   // [B,32,32] fp32
    const int waves = (Btot + 3) / 4;      // 4 batches per wave (strided)
    const int blocks = (waves + 3) / 4;    // 4 waves per block
    dim3 grid(blocks), block(256);
    hipLaunchKernelGGL(attn32, grid, block, 0, stream,
                       x, Wk, bk, Wq, bq, Wv, bv, Wp, bp, out, Btot);
}

// Round 7
// 58.045 us; speedup vs baseline: 1.2119x; 1.0066x over previous
//
#include <hip/hip_runtime.h>

typedef __bf16 bf16x8 __attribute__((ext_vector_type(8)));
typedef float  f32x16 __attribute__((ext_vector_type(16)));
typedef float  f32x4v __attribute__((ext_vector_type(4)));
typedef unsigned int uint4v __attribute__((ext_vector_type(4)));

#define MFMA32(A, B, C) __builtin_amdgcn_mfma_f32_32x32x16_bf16((A), (B), (C), 0, 0, 0)

__device__ __forceinline__ bf16x8 load8_bf(const float* __restrict__ p, float scale) {
    const float4 a = *reinterpret_cast<const float4*>(p);
    const float4 b = *reinterpret_cast<const float4*>(p + 4);
    bf16x8 r;
    r[0] = (__bf16)(a.x * scale); r[1] = (__bf16)(a.y * scale);
    r[2] = (__bf16)(a.z * scale); r[3] = (__bf16)(a.w * scale);
    r[4] = (__bf16)(b.x * scale); r[5] = (__bf16)(b.y * scale);
    r[6] = (__bf16)(b.z * scale); r[7] = (__bf16)(b.w * scale);
    return r;
}

__device__ __forceinline__ unsigned pack2(float a, float b) {
    unsigned la = (unsigned)__builtin_bit_cast(unsigned short, (__bf16)a);
    unsigned lb = (unsigned)__builtin_bit_cast(unsigned short, (__bf16)b);
    return la | (lb << 16);
}

__device__ __forceinline__ void swap32(unsigned& a, unsigned& b) {
#if __has_builtin(__builtin_amdgcn_permlane32_swap)
    auto r = __builtin_amdgcn_permlane32_swap(a, b, false, false);
    a = r[0]; b = r[1];
#else
    asm("v_permlane32_swap_b32 %0, %1" : "+v"(a), "+v"(b));
#endif
}

// C-layout acc (lane holds M[col][r(e,hi)], r(e,hi)=(e&3)+8*(e>>2)+4*hi)
// -> MFMA A/B fragments (lane holds M[col][k], f0: k=hi*8+q, f1: k=16+hi*8+q).
// PROVEN (R2/R4/R5 passed, absmax 0.047).
__device__ __forceinline__ void rearrange(const f32x16& a, bf16x8& f0, bf16x8& f1) {
    unsigned D0 = pack2(a[0], a[1]),   D1 = pack2(a[2], a[3]);
    unsigned D2 = pack2(a[4], a[5]),   D3 = pack2(a[6], a[7]);
    unsigned D4 = pack2(a[8], a[9]),   D5 = pack2(a[10], a[11]);
    unsigned D6 = pack2(a[12], a[13]), D7 = pack2(a[14], a[15]);
    swap32(D0, D2); swap32(D1, D3); swap32(D4, D6); swap32(D5, D7);
    f0 = __builtin_bit_cast(bf16x8, uint4v{D0, D1, D2, D3});
    f1 = __builtin_bit_cast(bf16x8, uint4v{D4, D5, D6, D7});
}

__device__ __forceinline__ void ld4(const float* __restrict__ p,
                                    float4& r0, float4& r1, float4& r2, float4& r3) {
    r0 = *reinterpret_cast<const float4*>(p);
    r1 = *reinterpret_cast<const float4*>(p + 4);
    r2 = *reinterpret_cast<const float4*>(p + 16);
    r3 = *reinterpret_cast<const float4*>(p + 20);
}

__device__ __forceinline__ void cvt8(const float4& a, const float4& b, bf16x8& f) {
    f[0] = (__bf16)a.x; f[1] = (__bf16)a.y; f[2] = (__bf16)a.z; f[3] = (__bf16)a.w;
    f[4] = (__bf16)b.x; f[5] = (__bf16)b.y; f[6] = (__bf16)b.z; f[7] = (__bf16)b.w;
}

// R2-proven math + loop/prefetch; ONE change: block-cooperative coalesced
// stores. The block's 4 waves handle 4 consecutive batches per iteration;
// outputs stage through a 16 KiB LDS tile [t][b_local][c] and are stored as
// 512-B contiguous segments (4x fewer, 4x larger write requests).
__global__ __launch_bounds__(256) void attn32(
    const float* __restrict__ x,
    const float* __restrict__ Wk, const float* __restrict__ bk,
    const float* __restrict__ Wq, const float* __restrict__ bq,
    const float* __restrict__ Wv, const float* __restrict__ bv,
    const float* __restrict__ Wp, const float* __restrict__ bp,
    float* __restrict__ out, int Btot)
{
    __shared__ float ldso[4096];  // [t][b_local][c] = [32][4][32] f32 = 16 KiB

    const int tid  = threadIdx.x;
    const int lane = tid & 63;
    const int col  = lane & 31;
    const int hi   = lane >> 5;
    const int wave = tid >> 6;

    const int nw    = gridDim.x * 4;
    const int base0 = blockIdx.x * 4;
    if (base0 >= Btot) return;  // uniform per block — barrier-safe

    // fold 1/sqrt(32)*log2(e) into Q so softmax uses exp2 directly
    const float SC = 0.17677669529663687f * 1.4426950408889634f;

    const int wrow = col * 32 + hi * 8;
    const bf16x8 wk0 = load8_bf(Wk + wrow, 1.f), wk1 = load8_bf(Wk + wrow + 16, 1.f);
    const bf16x8 wq0 = load8_bf(Wq + wrow, SC),  wq1 = load8_bf(Wq + wrow + 16, SC);
    const bf16x8 wv0 = load8_bf(Wv + wrow, 1.f), wv1 = load8_bf(Wv + wrow + 16, 1.f);
    const bf16x8 wp0 = load8_bf(Wp + wrow, 1.f), wp1 = load8_bf(Wp + wrow + 16, 1.f);

    f32x16 bk16, bq16, bv16;
#pragma unroll
    for (int e = 0; e < 16; ++e) {
        const int r = (e & 3) + 8 * (e >> 2) + 4 * hi;
        bk16[e] = bk[r];
        bq16[e] = bq[r] * SC;
        bv16[e] = bv[r];
    }
    const float bpv = bp[col];

    // prologue prefetch (batch for iteration 0)
    float4 A0, A1, A2, A3;
    {
        const int bw0 = base0 + wave;
        if (bw0 < Btot) ld4(x + (size_t)bw0 * 1024 + wrow, A0, A1, A2, A3);
    }

    for (int b0 = base0; b0 < Btot; b0 += nw) {
        const int bw  = b0 + wave;
        const bool act = bw < Btot;

        bf16x8 xa0, xa1;
        cvt8(A0, A1, xa0);
        cvt8(A2, A3, xa1);
        // issue next-iteration prefetch immediately (hide under compute)
        const int nb = bw + nw;
        if (nb < Btot) ld4(x + (size_t)nb * 1024 + wrow, A0, A1, A2, A3);

        if (act) {
            f32x16 acc;

            // K^T = Wk * X^T + bk
            acc = bk16; acc = MFMA32(wk0, xa0, acc); acc = MFMA32(wk1, xa1, acc);
            bf16x8 ka0, ka1; rearrange(acc, ka0, ka1);

            // Q^T (scale+log2e folded)
            acc = bq16; acc = MFMA32(wq0, xa0, acc); acc = MFMA32(wq1, xa1, acc);
            bf16x8 qb0, qb1; rearrange(acc, qb0, qb1);

            // S^T = K * Q^T : lane (query=col) holds S'[query][key=r(e,hi)]
            f32x16 s;
#pragma unroll
            for (int e = 0; e < 16; ++e) s[e] = 0.f;
            s = MFMA32(ka0, qb0, s);
            s = MFMA32(ka1, qb1, s);

            // V^T
            acc = bv16; acc = MFMA32(wv0, xa0, acc); acc = MFMA32(wv1, xa1, acc);
            bf16x8 vb0, vb1; rearrange(acc, vb0, vb1);

            // causal mask + max-subtracted softmax (R2-proven)
            f32x16 pv;
            {
                float sv[16];
                float m = -3.0e38f;
#pragma unroll
                for (int e = 0; e < 16; ++e) {
                    const int j = (e & 3) + 8 * (e >> 2) + 4 * hi;
                    sv[e] = (j <= col) ? s[e] : -__builtin_inff();
                    m = fmaxf(m, sv[e]);
                }
                m = fmaxf(m, __shfl_xor(m, 32));
                float pe[16];
                float sum = 0.f;
#pragma unroll
                for (int e = 0; e < 16; ++e) { pe[e] = __builtin_amdgcn_exp2f(sv[e] - m); sum += pe[e]; }
                sum += __shfl_xor(sum, 32);
                const float inv = __builtin_amdgcn_rcpf(sum);
#pragma unroll
                for (int e = 0; e < 16; ++e) pv[e] = pe[e] * inv;
            }
            bf16x8 pa0, pa1; rearrange(pv, pa0, pa1);

            // Y^T = V * P^T
            f32x16 yt;
#pragma unroll
            for (int e = 0; e < 16; ++e) yt[e] = 0.f;
            yt = MFMA32(vb0, pa0, yt);
            yt = MFMA32(vb1, pa1, yt);
            bf16x8 ya0, ya1; rearrange(yt, ya0, ya1);

            // out = Y * Wp^T + bp
            f32x16 o;
#pragma unroll
            for (int e = 0; e < 16; ++e) o[e] = bpv;
            o = MFMA32(ya0, wp0, o);
            o = MFMA32(ya1, wp1, o);

            // stage to LDS [t][b_local][c]: conflict-free (32 consecutive 4B
            // per half-wave; 2-way across halves is free)
            float* const lw = ldso + wave * 32 + col;
#pragma unroll
            for (int e = 0; e < 16; ++e) {
                const int r = (e & 3) + 8 * (e >> 2) + 4 * hi;
                lw[r * 128] = o[e];
            }
        }

        __syncthreads();

        // cooperative store: 1024 float4 chunks, consecutive tid -> consecutive
        // addresses; each instr covers two contiguous 512-B segments.
        // chunk = t*32 + b_local*8 + c4 ; global f4 index = t*2^18 + (b0+bl)*8 + c4
        {
            const f32x4v* const lr = (const f32x4v*)ldso;
            f32x4v* const og = (f32x4v*)out;
#pragma unroll
            for (int k2 = 0; k2 < 4; ++k2) {
                const int chunk = tid + k2 * 256;
                const int t  = chunk >> 5;
                const int bl = (chunk >> 3) & 3;
                const int c4 = chunk & 7;
                if (b0 + bl < Btot) {
                    __builtin_nontemporal_store(
                        lr[chunk], og + (((size_t)t << 18) + (size_t)(b0 + bl) * 8 + c4));
                }
            }
        }

        __syncthreads();  // WAR: LDS reads done before next iteration's writes
    }
}

extern "C" void kernel_launch(void* const* d_in, const int* in_sizes, int n_in,
                              void* d_out, int out_size, void* d_ws, size_t ws_size,
                              hipStream_t stream) {
    const float* x  = (const float*)d_in[0];
    const float* Wk = (const float*)d_in[1];
    const float* bk = (const float*)d_in[2];
    const float* Wq = (const float*)d_in[3];
    const float* bq = (const float*)d_in[4];
    const float* Wv = (const float*)d_in[5];
    const float* bv = (const float*)d_in[6];
    const float* Wp = (const float*)d_in[7];
    const float* bp = (const float*)d_in[8];
    float* out = (float*)d_out;

    const int Btot = in_sizes[0] / 1024;   // [B,32,32] fp32
    const int waves = (Btot + 3) / 4;      // 4 batches per wave across iterations
    int blocks = (waves + 3) / 4;          // 4 waves per block
    if (blocks > 2048) blocks = 2048;      // 4 iterations/wave at B=32768
    dim3 grid(blocks), block(256);
    hipLaunchKernelGGL(attn32, grid, block, 0, stream,
                       x, Wk, bk, Wq, bq, Wv, bv, Wp, bp, out, Btot);
}

// Round 8
// 51.459 us; speedup vs baseline: 1.3669x; 1.1280x over previous
//
#include <hip/hip_runtime.h>

typedef __bf16 bf16x8 __attribute__((ext_vector_type(8)));
typedef float  f32x16 __attribute__((ext_vector_type(16)));
typedef unsigned int uint4v __attribute__((ext_vector_type(4)));

#define MFMA32(A, B, C) __builtin_amdgcn_mfma_f32_32x32x16_bf16((A), (B), (C), 0, 0, 0)

__device__ __forceinline__ bf16x8 load8_bf(const float* __restrict__ p, float scale) {
    const float4 a = *reinterpret_cast<const float4*>(p);
    const float4 b = *reinterpret_cast<const float4*>(p + 4);
    bf16x8 r;
    r[0] = (__bf16)(a.x * scale); r[1] = (__bf16)(a.y * scale);
    r[2] = (__bf16)(a.z * scale); r[3] = (__bf16)(a.w * scale);
    r[4] = (__bf16)(b.x * scale); r[5] = (__bf16)(b.y * scale);
    r[6] = (__bf16)(b.z * scale); r[7] = (__bf16)(b.w * scale);
    return r;
}

__device__ __forceinline__ unsigned pack2(float a, float b) {
    unsigned la = (unsigned)__builtin_bit_cast(unsigned short, (__bf16)a);
    unsigned lb = (unsigned)__builtin_bit_cast(unsigned short, (__bf16)b);
    return la | (lb << 16);
}

__device__ __forceinline__ void swap32(unsigned& a, unsigned& b) {
#if __has_builtin(__builtin_amdgcn_permlane32_swap)
    auto r = __builtin_amdgcn_permlane32_swap(a, b, false, false);
    a = r[0]; b = r[1];
#else
    asm("v_permlane32_swap_b32 %0, %1" : "+v"(a), "+v"(b));
#endif
}

// rearrange(D in C-layout) = A-fragments of D^T  (PROVEN R2/R4/R5/R7):
// input: lane holds D[r(e,hi)][col], r(e,hi)=(e&3)+8*(e>>2)+4*hi
// output: lane holds D^T[col][k] = D[k][col]; f0: k=hi*8+q, f1: k=16+hi*8+q.
// As A-operand a frag F encodes A[lane][k]=F[k]; as B-operand B[k][lane]=F[k].
__device__ __forceinline__ void rearrange(const f32x16& a, bf16x8& f0, bf16x8& f1) {
    unsigned D0 = pack2(a[0], a[1]),   D1 = pack2(a[2], a[3]);
    unsigned D2 = pack2(a[4], a[5]),   D3 = pack2(a[6], a[7]);
    unsigned D4 = pack2(a[8], a[9]),   D5 = pack2(a[10], a[11]);
    unsigned D6 = pack2(a[12], a[13]), D7 = pack2(a[14], a[15]);
    swap32(D0, D2); swap32(D1, D3); swap32(D4, D6); swap32(D5, D7);
    f0 = __builtin_bit_cast(bf16x8, uint4v{D0, D1, D2, D3});
    f1 = __builtin_bit_cast(bf16x8, uint4v{D4, D5, D6, D7});
}

__device__ __forceinline__ void ld4(const float* __restrict__ p,
                                    float4& r0, float4& r1, float4& r2, float4& r3) {
    r0 = *reinterpret_cast<const float4*>(p);
    r1 = *reinterpret_cast<const float4*>(p + 4);
    r2 = *reinterpret_cast<const float4*>(p + 16);
    r3 = *reinterpret_cast<const float4*>(p + 20);
}

__device__ __forceinline__ void cvt8(const float4& a, const float4& b, bf16x8& f) {
    f[0] = (__bf16)a.x; f[1] = (__bf16)a.y; f[2] = (__bf16)a.z; f[3] = (__bf16)a.w;
    f[4] = (__bf16)b.x; f[5] = (__bf16)b.y; f[6] = (__bf16)b.z; f[7] = (__bf16)b.w;
}

// R2 chassis (loop+prefetch+scattered stores) with algebraic restructure:
//   S^T = X*NN*X^T + (X*Wk^T*bq)*1^T  [per-query terms dropped: softmax-inv]
//     NN = Wk^T*Wq (SC folded), precomputed per wave (2 setup MFMAs)
//   out = P*R^T + bp,  R^T = V^T*Wp^T,  V = X*Wv^T + 1*bv^T
// Per batch: 10 MFMAs (was 12), 4 rearranges (was 5), no K/Q stages.
__global__ __launch_bounds__(256) void attn32(
    const float* __restrict__ x,
    const float* __restrict__ Wk, const float* __restrict__ bk,
    const float* __restrict__ Wq, const float* __restrict__ bq,
    const float* __restrict__ Wv, const float* __restrict__ bv,
    const float* __restrict__ Wp, const float* __restrict__ bp,
    float* __restrict__ out, int Btot)
{
    const int lane = threadIdx.x & 63;
    const int col  = lane & 31;
    const int hi   = lane >> 5;

    const int gw = blockIdx.x * 4 + (threadIdx.x >> 6);
    const int nw = gridDim.x * 4;
    if (gw >= Btot) return;

    // fold 1/sqrt(32)*log2(e) so softmax uses exp2 directly
    const float SC = 0.17677669529663687f * 1.4426950408889634f;

    const int wrow = col * 32 + hi * 8;

    // prologue prefetch of first batch (overlaps all setup below)
    float4 A0, A1, A2, A3;
    ld4(x + (size_t)gw * 1024 + wrow, A0, A1, A2, A3);

    // row-loaded weights (as B-operands: B = W^T)
    const bf16x8 wv0 = load8_bf(Wv + wrow, 1.f), wv1 = load8_bf(Wv + wrow + 16, 1.f);
    const bf16x8 wp0 = load8_bf(Wp + wrow, 1.f), wp1 = load8_bf(Wp + wrow + 16, 1.f);

    // column-loaded Wk, Wq (setup only): lane holds W[k][col], k=hi*8+q (+16)
    bf16x8 wkc0, wkc1, wqc0, wqc1, bqb0, bqb1;
#pragma unroll
    for (int q = 0; q < 8; ++q) {
        wkc0[q] = (__bf16)Wk[(hi * 8 + q) * 32 + col];
        wkc1[q] = (__bf16)Wk[(16 + hi * 8 + q) * 32 + col];
        wqc0[q] = (__bf16)(SC * Wq[(hi * 8 + q) * 32 + col]);
        wqc1[q] = (__bf16)(SC * Wq[(16 + hi * 8 + q) * 32 + col]);
        bqb0[q] = (__bf16)(SC * bq[hi * 8 + q]);
        bqb1[q] = (__bf16)(SC * bq[16 + hi * 8 + q]);
    }

    f32x16 acc;
#pragma unroll
    for (int e = 0; e < 16; ++e) acc[e] = 0.f;

    // NN^T = (SC*Wq)^T * Wk  (contraction over out-channel = rows of both)
    acc = MFMA32(wqc0, wkc0, acc);
    acc = MFMA32(wqc1, wkc1, acc);
    bf16x8 nA0, nA1; rearrange(acc, nA0, nA1);  // A-frags of NN

    // u*1^T = Wk^T * (SC*bq*1^T): per-element u16[e] = SC*(Wk^T bq)[r(e,hi)]
#pragma unroll
    for (int e = 0; e < 16; ++e) acc[e] = 0.f;
    acc = MFMA32(wkc0, bqb0, acc);
    acc = MFMA32(wkc1, bqb1, acc);
    const f32x16 u16 = acc;

    const float bvv = bv[col];
    const float bpv = bp[col];

    for (int b = gw; b < Btot; b += nw) {
        bf16x8 xa0, xa1;   // lane holds X[col][k]; as A: X, as B: X^T
        cvt8(A0, A1, xa0);
        cvt8(A2, A3, xa1);
        const int nb = b + nw;
        if (nb < Btot) ld4(x + (size_t)nb * 1024 + wrow, A0, A1, A2, A3);

        // V = X*Wv^T + 1*bv^T  (C-layout: col=lane=c, row=t)
#pragma unroll
        for (int e = 0; e < 16; ++e) acc[e] = bvv;
        acc = MFMA32(xa0, wv0, acc);
        acc = MFMA32(xa1, wv1, acc);
        bf16x8 vT0, vT1; rearrange(acc, vT0, vT1);  // A-frags of V^T

        // R^T = V^T * Wp^T  (C-layout: col=lane=c', row=c)
#pragma unroll
        for (int e = 0; e < 16; ++e) acc[e] = 0.f;
        acc = MFMA32(vT0, wp0, acc);
        acc = MFMA32(vT1, wp1, acc);
        bf16x8 rB0, rB1; rearrange(acc, rB0, rB1);  // as B: R^T

        // H = NN*X^T + u*1^T  (C-layout: col=lane=t, row=a)
        acc = u16;
        acc = MFMA32(nA0, xa0, acc);
        acc = MFMA32(nA1, xa1, acc);
        bf16x8 hb0, hb1; rearrange(acc, hb0, hb1);  // as B: H

        // S^T(core) = X*H : col=lane=query t, row=key t'
        f32x16 s;
#pragma unroll
        for (int e = 0; e < 16; ++e) s[e] = 0.f;
        s = MFMA32(xa0, hb0, s);
        s = MFMA32(xa1, hb1, s);

        // causal mask + max-subtracted softmax (R2-proven; exp2, SC pre-folded)
        f32x16 pv;
        {
            float sv[16];
            float m = -3.0e38f;
#pragma unroll
            for (int e = 0; e < 16; ++e) {
                const int j = (e & 3) + 8 * (e >> 2) + 4 * hi;
                sv[e] = (j <= col) ? s[e] : -__builtin_inff();
                m = fmaxf(m, sv[e]);
            }
            m = fmaxf(m, __shfl_xor(m, 32));
            float pe[16];
            float sum = 0.f;
#pragma unroll
            for (int e = 0; e < 16; ++e) { pe[e] = __builtin_amdgcn_exp2f(sv[e] - m); sum += pe[e]; }
            sum += __shfl_xor(sum, 32);
            const float inv = __builtin_amdgcn_rcpf(sum);
#pragma unroll
            for (int e = 0; e < 16; ++e) pv[e] = pe[e] * inv;
        }
        bf16x8 pa0, pa1; rearrange(pv, pa0, pa1);  // A-frags of P

        // out = P*R^T + 1*bp^T : col=lane=c', row=t
        f32x16 o;
#pragma unroll
        for (int e = 0; e < 16; ++e) o[e] = bpv;
        o = MFMA32(pa0, rB0, o);
        o = MFMA32(pa1, rB1, o);

        // out flat [T, B, C]: element r*2^20 + b*32 + col (R2-proven)
        float* const ob = out + (size_t)b * 32 + col;
#pragma unroll
        for (int e = 0; e < 16; ++e) {
            const int r = (e & 3) + 8 * (e >> 2) + 4 * hi;
            __builtin_nontemporal_store(o[e], ob + ((size_t)r << 20));
        }
    }
}

extern "C" void kernel_launch(void* const* d_in, const int* in_sizes, int n_in,
                              void* d_out, int out_size, void* d_ws, size_t ws_size,
                              hipStream_t stream) {
    const float* x  = (const float*)d_in[0];
    const float* Wk = (const float*)d_in[1];
    const float* bk = (const float*)d_in[2];
    const float* Wq = (const float*)d_in[3];
    const float* bq = (const float*)d_in[4];
    const float* Wv = (const float*)d_in[5];
    const float* bv = (const float*)d_in[6];
    const float* Wp = (const float*)d_in[7];
    const float* bp = (const float*)d_in[8];
    float* out = (float*)d_out;

    const int Btot = in_sizes[0] / 1024;  // [B,32,32] fp32
    dim3 grid(2048), block(256);
    hipLaunchKernelGGL(attn32, grid, block, 0, stream,
                       x, Wk, bk, Wq, bq, Wv, bv, Wp, bp, out, Btot);
}